// Round 2
// baseline (312.399 us; speedup 1.0000x reference)
//
#include <hip/hip_runtime.h>
#include <math.h>

#define Bsz 64
#define Himg 224
#define HS (Himg*Himg)        // 50176
#define PW 111
#define PP (PW*PW)            // 12321
#define Fn 8
#define FEAT (Fn*PP)          // 98568
#define N1 512
#define N2 256
#define N3 1000
#define KC 16
#define CHUNK 384
#define NCH 257               // ceil(FEAT/CHUNK)

// ---------------- channel sum: s[b,y,x] = sum_c x[b,c,y,x] (float4) --------
__global__ void k_chsum(const float4* __restrict__ x, float4* __restrict__ s) {
  int i = blockIdx.x * 256 + threadIdx.x;
  const int HQ = HS / 4;
  if (i >= Bsz * HQ) return;
  int b = i / HQ, p = i - b * HQ;
  const float4* xb = x + (size_t)b * 3 * HQ + p;
  float4 a = xb[0], c = xb[HQ], d = xb[2 * HQ];
  s[i] = make_float4(a.x + c.x + d.x, a.y + c.y + d.y,
                     a.z + c.z + d.z, a.w + c.w + d.w);
}

// ------------- conv3x3 (8 filt) + relu + maxpool2x2 -> flat ----------------
__global__ void k_convpool(const float* __restrict__ s, const float* __restrict__ filt,
                           float* __restrict__ flat) {
  int i = blockIdx.x * 256 + threadIdx.x;
  if (i >= Bsz * PP) return;
  int b = i / PP, r = i - b * PP;
  int py = r / PW, px = r - py * PW;
  const float* sp = s + (size_t)b * HS + (size_t)(2 * py) * Himg + 2 * px;
  float p[4][4];
#pragma unroll
  for (int dy = 0; dy < 4; dy++)
#pragma unroll
    for (int dx = 0; dx < 4; dx++)
      p[dy][dx] = sp[dy * Himg + dx];
  float* outb = flat + (size_t)b * FEAT + r;
#pragma unroll
  for (int f = 0; f < Fn; f++) {
    float mx = 0.f;  // relu floor: max(0, conv...) == max over relu'd convs
#pragma unroll
    for (int oy = 0; oy < 2; oy++)
#pragma unroll
      for (int ox = 0; ox < 2; ox++) {
        float c = 0.f;
#pragma unroll
        for (int dy = 0; dy < 3; dy++)
#pragma unroll
          for (int dx = 0; dx < 3; dx++)
            c = fmaf(p[oy + dy][ox + dx], filt[f * 9 + dy * 3 + dx], c);
        mx = fmaxf(mx, c);
      }
    outb[(size_t)f * PP] = mx;
  }
}

// ---------------- GEMM1 split-K partials: (64 x K) @ (K x 512) -------------
// grid (4 n-tiles of 128 cols, NCH k-chunks), block 256 threads.
// Block tile: 64m x 128n. Thread: 8m x 4n. Both A^T and W staged in LDS,
// double-buffered with register prefetch; 1 barrier per K-step.
__global__ void __launch_bounds__(256, 2) k_gemm1(const float* __restrict__ A,
                                                  const float* __restrict__ W,
                                                  float* __restrict__ partial) {
  __shared__ float At[2][KC][64];    // [k][m]
  __shared__ float Wt[2][KC][128];   // [k][n]
  const int t = threadIdx.x;
  const int col0 = blockIdx.x * 128;
  const int c = blockIdx.y;
  const int k0 = c * CHUNK;
  const int kend = min(k0 + CHUNK, FEAT);
  // compute mapping
  const int cg = t & 31;       // 32 col-groups of 4 cols
  const int mg = t >> 5;       // 8 m-groups of 8 rows
  // staging mapping
  const int ms = t & 63;       // A: row m
  const int kq = (t >> 6) * 4; // A: 4 consecutive k
  const int kr = t >> 4;       // W: row k (16 rows)
  const int cq = (t & 15) * 8; // W: 8 consecutive cols

  float4 pa, pw0, pw1;

  auto loadA = [&](int kt) {
    int kg = kt + kq;
    pa = (kg < kend) ? *(const float4*)(A + (size_t)ms * FEAT + kg)
                     : make_float4(0.f, 0.f, 0.f, 0.f);
  };
  auto loadW = [&](int kt) {
    int kg = kt + kr;
    if (kg < kend) {
      const float* wp = W + (size_t)kg * N1 + col0 + cq;
      pw0 = *(const float4*)wp;
      pw1 = *(const float4*)(wp + 4);
    } else {
      pw0 = pw1 = make_float4(0.f, 0.f, 0.f, 0.f);
    }
  };
  auto storeT = [&](int buf) {
    At[buf][kq + 0][ms] = pa.x;
    At[buf][kq + 1][ms] = pa.y;
    At[buf][kq + 2][ms] = pa.z;
    At[buf][kq + 3][ms] = pa.w;
    *(float4*)&Wt[buf][kr][cq] = pw0;
    *(float4*)&Wt[buf][kr][cq + 4] = pw1;
  };

  float4 acc[8];
#pragma unroll
  for (int i = 0; i < 8; i++) acc[i] = make_float4(0.f, 0.f, 0.f, 0.f);

  loadA(k0);
  loadW(k0);
  storeT(0);
  __syncthreads();

  const int nstep = (kend - k0 + KC - 1) / KC;
  for (int s = 0; s < nstep; s++) {
    const int buf = s & 1;
    const bool more = (s + 1) < nstep;
    if (more) {               // issue next-tile global loads early
      loadA(k0 + (s + 1) * KC);
      loadW(k0 + (s + 1) * KC);
    }
#pragma unroll
    for (int k = 0; k < KC; k++) {
      float4 a0 = *(const float4*)&At[buf][k][mg * 8];
      float4 a1 = *(const float4*)&At[buf][k][mg * 8 + 4];
      float4 w = *(const float4*)&Wt[buf][k][cg * 4];
#pragma unroll
      for (int i = 0; i < 4; i++) {
        float a = (i == 0) ? a0.x : (i == 1) ? a0.y : (i == 2) ? a0.z : a0.w;
        acc[i].x = fmaf(a, w.x, acc[i].x);
        acc[i].y = fmaf(a, w.y, acc[i].y);
        acc[i].z = fmaf(a, w.z, acc[i].z);
        acc[i].w = fmaf(a, w.w, acc[i].w);
      }
#pragma unroll
      for (int i = 0; i < 4; i++) {
        float a = (i == 0) ? a1.x : (i == 1) ? a1.y : (i == 2) ? a1.z : a1.w;
        acc[4 + i].x = fmaf(a, w.x, acc[4 + i].x);
        acc[4 + i].y = fmaf(a, w.y, acc[4 + i].y);
        acc[4 + i].z = fmaf(a, w.z, acc[4 + i].z);
        acc[4 + i].w = fmaf(a, w.w, acc[4 + i].w);
      }
    }
    if (more) storeT(buf ^ 1);
    __syncthreads();
  }

  float* pp = partial + ((size_t)c * Bsz + mg * 8) * N1 + col0 + cg * 4;
#pragma unroll
  for (int i = 0; i < 8; i++)
    *(float4*)(pp + (size_t)i * N1) = acc[i];
}

// -------------- reduce partials + bias + relu -> h1 [64,512] ---------------
__global__ void k_red1(const float* __restrict__ partial, const float* __restrict__ b1,
                       float* __restrict__ h1) {
  int i = blockIdx.x * 256 + threadIdx.x;
  if (i >= Bsz * N1) return;
  float sum = 0.f;
  for (int c = 0; c < NCH; c++) sum += partial[(size_t)c * Bsz * N1 + i];
  int n = i & (N1 - 1);
  h1[i] = fmaxf(sum + b1[n], 0.f);
}

// -------------- GEMM2: h2 = relu(h1 @ W2 + b2), [64,256] -------------------
__global__ void __launch_bounds__(256) k_gemm2(const float* __restrict__ h1,
                                               const float* __restrict__ W2,
                                               const float* __restrict__ b2,
                                               float* __restrict__ h2) {
  const int m = blockIdx.x;
  const int t = threadIdx.x;
  __shared__ float a[N1];
  a[t] = h1[(size_t)m * N1 + t];
  a[256 + t] = h1[(size_t)m * N1 + 256 + t];
  __syncthreads();
  float sum = b2[t];
#pragma unroll 8
  for (int k = 0; k < N1; k++) sum = fmaf(a[k], W2[(size_t)k * N2 + t], sum);
  h2[(size_t)m * N2 + t] = fmaxf(sum, 0.f);
}

// -------------- GEMM3 + softmax: out = softmax(h2 @ Wo + bo) ---------------
__global__ void __launch_bounds__(256) k_out(const float* __restrict__ h2,
                                             const float* __restrict__ Wo,
                                             const float* __restrict__ bo,
                                             float* __restrict__ out) {
  const int m = blockIdx.x;
  const int t = threadIdx.x;
  __shared__ float a[N2];
  __shared__ float red[8];
  a[t] = h2[(size_t)m * N2 + t];
  __syncthreads();
  float vals[4];
  float vmax = -3.4e38f;
#pragma unroll
  for (int j = 0; j < 4; j++) {
    int n = j * 256 + t;
    float sum = -3.4e38f;
    if (n < N3) {
      sum = bo[n];
#pragma unroll 8
      for (int k = 0; k < N2; k++) sum = fmaf(a[k], Wo[(size_t)k * N3 + n], sum);
    }
    vals[j] = sum;
    vmax = fmaxf(vmax, sum);
  }
#pragma unroll
  for (int off = 32; off > 0; off >>= 1) vmax = fmaxf(vmax, __shfl_xor(vmax, off));
  const int wid = t >> 6;
  if ((t & 63) == 0) red[wid] = vmax;
  __syncthreads();
  vmax = fmaxf(fmaxf(red[0], red[1]), fmaxf(red[2], red[3]));
  float ev[4];
  float esum = 0.f;
#pragma unroll
  for (int j = 0; j < 4; j++) {
    int n = j * 256 + t;
    float e = (n < N3) ? __expf(vals[j] - vmax) : 0.f;
    ev[j] = e;
    esum += e;
  }
#pragma unroll
  for (int off = 32; off > 0; off >>= 1) esum += __shfl_xor(esum, off);
  if ((t & 63) == 0) red[4 + wid] = esum;
  __syncthreads();
  esum = red[4] + red[5] + red[6] + red[7];
  float inv = 1.f / esum;
#pragma unroll
  for (int j = 0; j < 4; j++) {
    int n = j * 256 + t;
    if (n < N3) out[(size_t)m * N3 + n] = ev[j] * inv;
  }
}

extern "C" void kernel_launch(void* const* d_in, const int* in_sizes, int n_in,
                              void* d_out, int out_size, void* d_ws, size_t ws_size,
                              hipStream_t stream) {
  const float* x = (const float*)d_in[0];
  const float* filters = (const float*)d_in[1];
  const float* W1 = (const float*)d_in[2];
  const float* b1 = (const float*)d_in[3];
  const float* W2 = (const float*)d_in[4];
  const float* b2 = (const float*)d_in[5];
  const float* Wo = (const float*)d_in[6];
  const float* bo = (const float*)d_in[7];
  float* out = (float*)d_out;

  float* ws = (float*)d_ws;
  float* s = ws;                                    // 64*224*224
  float* flat = s + (size_t)Bsz * HS;               // 64*98568
  float* partial = flat + (size_t)Bsz * FEAT;       // NCH*64*512
  float* h1 = partial + (size_t)NCH * Bsz * N1;     // 64*512
  float* h2 = h1 + (size_t)Bsz * N1;                // 64*256

  k_chsum<<<(Bsz * HS / 4 + 255) / 256, 256, 0, stream>>>((const float4*)x, (float4*)s);
  k_convpool<<<(Bsz * PP + 255) / 256, 256, 0, stream>>>(s, filters, flat);
  dim3 g1(4, NCH);
  k_gemm1<<<g1, 256, 0, stream>>>(flat, W1, partial);
  k_red1<<<(Bsz * N1 + 255) / 256, 256, 0, stream>>>(partial, b1, h1);
  k_gemm2<<<Bsz, 256, 0, stream>>>(h1, W2, b2, h2);
  k_out<<<Bsz, 256, 0, stream>>>(h2, Wo, bo, out);
}